// Round 1
// baseline (33516.925 us; speedup 1.0000x reference)
//
#include <hip/hip_runtime.h>
#include <math.h>

#define BB 4
#define TT 1024
#define DD 1024
#define HH 16
#define LL 6
#define OUTD 1024
#define DHH 64
#define MM (BB*TT)   // 4096

// ---------------------------------------------------------------- add pos
__global__ __launch_bounds__(256) void add_pos_kernel(
    const float* __restrict__ seq, const float* __restrict__ pos, float* __restrict__ x)
{
    int i = blockIdx.x * 256 + threadIdx.x;          // float4 index, total B*T*D/4
    const int TD4 = TT * DD / 4;
    float4 s = ((const float4*)seq)[i];
    float4 p = ((const float4*)pos)[i & (TD4 - 1)];
    float4 o = make_float4(s.x + p.x, s.y + p.y, s.z + p.z, s.w + p.w);
    ((float4*)x)[i] = o;
}

// ---------------------------------------------------------------- layernorm
__global__ __launch_bounds__(256) void ln_kernel(
    const float* __restrict__ x, const float* __restrict__ g,
    const float* __restrict__ b, float* __restrict__ out)
{
    __shared__ float red[8];
    int row = blockIdx.x;
    int tid = threadIdx.x;
    const float4* xr = (const float4*)(x + (size_t)row * DD);
    float4 v = xr[tid];
    float s  = v.x + v.y + v.z + v.w;
    float ss = v.x*v.x + v.y*v.y + v.z*v.z + v.w*v.w;
    #pragma unroll
    for (int o = 32; o > 0; o >>= 1) {
        s  += __shfl_down(s,  o, 64);
        ss += __shfl_down(ss, o, 64);
    }
    int wid = tid >> 6, lid = tid & 63;
    if (lid == 0) { red[wid] = s; red[4 + wid] = ss; }
    __syncthreads();
    float sum  = red[0] + red[1] + red[2] + red[3];
    float sums = red[4] + red[5] + red[6] + red[7];
    float mean = sum * (1.0f / DD);
    float var  = sums * (1.0f / DD) - mean * mean;
    float inv  = rsqrtf(var + 1e-5f);
    float4 gg = ((const float4*)g)[tid];
    float4 bb = ((const float4*)b)[tid];
    float4 o;
    o.x = (v.x - mean) * inv * gg.x + bb.x;
    o.y = (v.y - mean) * inv * gg.y + bb.y;
    o.z = (v.z - mean) * inv * gg.z + bb.z;
    o.w = (v.w - mean) * inv * gg.w + bb.w;
    ((float4*)(out + (size_t)row * DD))[tid] = o;
}

// ---------------------------------------------------------------- GEMM
// C[M,N] = act(A[M,K] @ W[K,N] + bias) (+ res). 64x64 tile, BK=16, 256 thr, 4x4/thread.
template<int ACT, bool RES>
__global__ __launch_bounds__(256) void gemm_kernel(
    const float* __restrict__ A, const float* __restrict__ W,
    const float* __restrict__ bias, const float* __restrict__ res,
    float* __restrict__ C, int M, int N, int K)
{
    __shared__ float As[16][64];
    __shared__ float Ws[16][64];
    int tid = threadIdx.x;
    int n0 = blockIdx.x * 64, m0 = blockIdx.y * 64;
    int tm = tid >> 4, tn = tid & 15;

    int am = tid >> 2;          // 0..63
    int ak = (tid & 3) * 4;     // 0,4,8,12
    int wk = tid >> 4;          // 0..15
    int wn = (tid & 15) * 4;    // 0..60

    const float* Ap = A + (size_t)(m0 + am) * K + ak;
    const float* Wp = W + (size_t)wk * N + n0 + wn;

    float acc[4][4] = {};
    for (int k0 = 0; k0 < K; k0 += 16) {
        float4 av = *(const float4*)(Ap + k0);
        float4 wv = *(const float4*)(Wp + (size_t)k0 * N);
        __syncthreads();
        As[ak + 0][am] = av.x;
        As[ak + 1][am] = av.y;
        As[ak + 2][am] = av.z;
        As[ak + 3][am] = av.w;
        *(float4*)&Ws[wk][wn] = wv;
        __syncthreads();
        #pragma unroll
        for (int kk = 0; kk < 16; kk++) {
            float a[4], w[4];
            *(float4*)a = *(const float4*)&As[kk][tm * 4];
            *(float4*)w = *(const float4*)&Ws[kk][tn * 4];
            #pragma unroll
            for (int i = 0; i < 4; i++)
                #pragma unroll
                for (int j = 0; j < 4; j++)
                    acc[i][j] += a[i] * w[j];
        }
    }

    int n = n0 + tn * 4;
    float4 bv = make_float4(0.f, 0.f, 0.f, 0.f);
    if (bias) bv = *(const float4*)(bias + n);
    #pragma unroll
    for (int i = 0; i < 4; i++) {
        int m = m0 + tm * 4 + i;
        float4 o;
        o.x = acc[i][0] + bv.x;
        o.y = acc[i][1] + bv.y;
        o.z = acc[i][2] + bv.z;
        o.w = acc[i][3] + bv.w;
        if (ACT == 1) {  // exact GELU
            o.x = 0.5f * o.x * (1.0f + erff(o.x * 0.70710678118654752f));
            o.y = 0.5f * o.y * (1.0f + erff(o.y * 0.70710678118654752f));
            o.z = 0.5f * o.z * (1.0f + erff(o.z * 0.70710678118654752f));
            o.w = 0.5f * o.w * (1.0f + erff(o.w * 0.70710678118654752f));
        }
        if (RES) {
            float4 r = *(const float4*)(res + (size_t)m * N + n);
            o.x += r.x; o.y += r.y; o.z += r.z; o.w += r.w;
        }
        *(float4*)(C + (size_t)m * N + n) = o;
    }
}

// ---------------------------------------------------------------- attention
// One block per (b,h,t): full-row softmax(q.K/8) then y = p.V. No mask (faithful).
__global__ __launch_bounds__(256) void attn_kernel(
    const float* __restrict__ q, const float* __restrict__ k,
    const float* __restrict__ v, float* __restrict__ y)
{
    __shared__ float qs[DHH];
    __shared__ float p[TT];
    __shared__ float red[8];
    __shared__ float yred[4][DHH];

    int bht = blockIdx.x;
    int t = bht & (TT - 1);
    int h = (bht >> 10) & (HH - 1);
    int b = bht >> 14;
    int tid = threadIdx.x;
    size_t base = (size_t)b * TT * DD + (size_t)h * DHH;

    if (tid < DHH) qs[tid] = q[base + (size_t)t * DD + tid];
    __syncthreads();

    float sc[4];
    float lmax = -1e30f;
    #pragma unroll
    for (int j = 0; j < 4; j++) {
        int s = tid + j * 256;
        const float* kr = k + base + (size_t)s * DD;
        float acc = 0.f;
        #pragma unroll
        for (int d0 = 0; d0 < DHH; d0 += 4) {
            float4 kv = *(const float4*)(kr + d0);
            acc += qs[d0] * kv.x + qs[d0+1] * kv.y + qs[d0+2] * kv.z + qs[d0+3] * kv.w;
        }
        sc[j] = acc * 0.125f;
        lmax = fmaxf(lmax, sc[j]);
    }
    #pragma unroll
    for (int o = 32; o > 0; o >>= 1) lmax = fmaxf(lmax, __shfl_down(lmax, o, 64));
    int wid = tid >> 6, lid = tid & 63;
    if (lid == 0) red[wid] = lmax;
    __syncthreads();
    float gmax = fmaxf(fmaxf(red[0], red[1]), fmaxf(red[2], red[3]));

    float lsum = 0.f;
    #pragma unroll
    for (int j = 0; j < 4; j++) {
        float e = __expf(sc[j] - gmax);
        p[tid + j * 256] = e;
        lsum += e;
    }
    #pragma unroll
    for (int o = 32; o > 0; o >>= 1) lsum += __shfl_down(lsum, o, 64);
    if (lid == 0) red[4 + wid] = lsum;
    __syncthreads();                       // also publishes p[]
    float inv = 1.0f / (red[4] + red[5] + red[6] + red[7]);

    int d = tid & 63;
    int chunk = tid >> 6;
    const float* vr = v + base + (size_t)(chunk * 256) * DD + d;
    float acc = 0.f;
    for (int s = 0; s < 256; s++) acc += p[chunk * 256 + s] * vr[(size_t)s * DD];
    yred[chunk][d] = acc;
    __syncthreads();
    if (tid < DHH) {
        float o = (yred[0][tid] + yred[1][tid] + yred[2][tid] + yred[3][tid]) * inv;
        y[base + (size_t)t * DD + tid] = o;
    }
}

// ---------------------------------------------------------------- launch
extern "C" void kernel_launch(void* const* d_in, const int* in_sizes, int n_in,
                              void* d_out, int out_size, void* d_ws, size_t ws_size,
                              hipStream_t stream)
{
    const float* seq    = (const float*)d_in[0];
    const float* pos    = (const float*)d_in[1];
    const float* ln1_g  = (const float*)d_in[2];
    const float* ln1_b  = (const float*)d_in[3];
    const float* wq     = (const float*)d_in[4];
    const float* bq     = (const float*)d_in[5];
    const float* wk     = (const float*)d_in[6];
    const float* bk     = (const float*)d_in[7];
    const float* wv     = (const float*)d_in[8];
    const float* bv     = (const float*)d_in[9];
    const float* wo     = (const float*)d_in[10];
    const float* bo     = (const float*)d_in[11];
    const float* ln2_g  = (const float*)d_in[12];
    const float* ln2_b  = (const float*)d_in[13];
    const float* w1     = (const float*)d_in[14];
    const float* b1     = (const float*)d_in[15];
    const float* w2     = (const float*)d_in[16];
    const float* b2     = (const float*)d_in[17];
    const float* lnf_g  = (const float*)d_in[18];
    const float* lnf_b  = (const float*)d_in[19];
    const float* w_head = (const float*)d_in[20];
    float* out = (float*)d_out;

    const size_t MSZ = (size_t)MM * DD;          // 4,194,304 floats
    float* ws = (float*)d_ws;
    float* x  = ws;              // activations (residual stream)
    float* h  = x  + MSZ;        // LN out / attention y (reused)
    float* qb = h  + MSZ;
    float* kb = qb + MSZ;
    float* vb = kb + MSZ;
    float* ub = vb + MSZ;        // MLP hidden, 16,777,216 floats
    // total: 37,748,736 floats = 151 MB

    dim3 blk(256);
    dim3 gemm_d(16, 64);    // N=1024
    dim3 gemm_4d(64, 64);   // N=4096

    add_pos_kernel<<<4096, blk, 0, stream>>>(seq, pos, x);

    for (int l = 0; l < LL; l++) {
        const size_t wofs = (size_t)l * DD * DD;
        const size_t bofs = (size_t)l * DD;
        const size_t w1ofs = (size_t)l * DD * 4 * DD;
        const size_t b1ofs = (size_t)l * 4 * DD;

        ln_kernel<<<MM, blk, 0, stream>>>(x, ln1_g + bofs, ln1_b + bofs, h);
        gemm_kernel<0,false><<<gemm_d, blk, 0, stream>>>(h, wq + wofs, bq + bofs, nullptr, qb, MM, DD, DD);
        gemm_kernel<0,false><<<gemm_d, blk, 0, stream>>>(h, wk + wofs, bk + bofs, nullptr, kb, MM, DD, DD);
        gemm_kernel<0,false><<<gemm_d, blk, 0, stream>>>(h, wv + wofs, bv + bofs, nullptr, vb, MM, DD, DD);
        attn_kernel<<<BB*HH*TT, blk, 0, stream>>>(qb, kb, vb, h);
        gemm_kernel<0,true><<<gemm_d, blk, 0, stream>>>(h, wo + wofs, bo + bofs, x, x, MM, DD, DD);
        ln_kernel<<<MM, blk, 0, stream>>>(x, ln2_g + bofs, ln2_b + bofs, h);
        gemm_kernel<1,false><<<gemm_4d, blk, 0, stream>>>(h, w1 + w1ofs, b1 + b1ofs, nullptr, ub, MM, 4*DD, DD);
        gemm_kernel<0,true><<<gemm_d, blk, 0, stream>>>(ub, w2 + w1ofs, b2 + bofs, x, x, MM, DD, 4*DD);
    }

    ln_kernel<<<MM, blk, 0, stream>>>(x, lnf_g, lnf_b, h);
    gemm_kernel<0,false><<<gemm_d, blk, 0, stream>>>(h, w_head, nullptr, nullptr, out, MM, OUTD, DD);
}

// Round 2
// 2578.387 us; speedup vs baseline: 12.9992x; 12.9992x over previous
//
#include <hip/hip_runtime.h>
#include <math.h>

#define BB 4
#define TT 1024
#define DD 1024
#define HH 16
#define LL 6
#define DHH 64
#define MM (BB*TT)   // 4096

typedef short bf16x8 __attribute__((ext_vector_type(8)));
typedef float floatx4 __attribute__((ext_vector_type(4)));

#define AS1 __attribute__((address_space(1)))
#define AS3 __attribute__((address_space(3)))

__device__ __forceinline__ void g2l16(const void* g, void* l) {
    __builtin_amdgcn_global_load_lds((const AS1 unsigned int*)g,
                                     (AS3 unsigned int*)l, 16, 0, 0);
}

__device__ __forceinline__ unsigned short f2bf(float f) {
    unsigned u = __builtin_bit_cast(unsigned, f);
    u += 0x7fffu + ((u >> 16) & 1u);
    return (unsigned short)(u >> 16);
}

// ---------------------------------------------------------------- add pos (fp32 out)
__global__ __launch_bounds__(256) void add_pos_kernel(
    const float* __restrict__ seq, const float* __restrict__ pos, float* __restrict__ x)
{
    int i = blockIdx.x * 256 + threadIdx.x;
    const int TD4 = TT * DD / 4;
    float4 s = ((const float4*)seq)[i];
    float4 p = ((const float4*)pos)[i & (TD4 - 1)];
    ((float4*)x)[i] = make_float4(s.x + p.x, s.y + p.y, s.z + p.z, s.w + p.w);
}

// ---------------------------------------------------------------- layernorm (fp32 in, bf16 out)
__global__ __launch_bounds__(256) void ln_kernel(
    const float* __restrict__ x, const float* __restrict__ g,
    const float* __restrict__ b, unsigned short* __restrict__ out)
{
    __shared__ float red[8];
    int row = blockIdx.x;
    int tid = threadIdx.x;
    const float4* xr = (const float4*)(x + (size_t)row * DD);
    float4 v = xr[tid];
    float s  = v.x + v.y + v.z + v.w;
    float ss = v.x*v.x + v.y*v.y + v.z*v.z + v.w*v.w;
    #pragma unroll
    for (int o = 32; o > 0; o >>= 1) {
        s  += __shfl_down(s,  o, 64);
        ss += __shfl_down(ss, o, 64);
    }
    int wid = tid >> 6, lid = tid & 63;
    if (lid == 0) { red[wid] = s; red[4 + wid] = ss; }
    __syncthreads();
    float sum  = red[0] + red[1] + red[2] + red[3];
    float sums = red[4] + red[5] + red[6] + red[7];
    float mean = sum * (1.0f / DD);
    float var  = sums * (1.0f / DD) - mean * mean;
    float inv  = rsqrtf(var + 1e-5f);
    float4 gg = ((const float4*)g)[tid];
    float4 bb = ((const float4*)b)[tid];
    ushort4 o4;
    o4.x = f2bf((v.x - mean) * inv * gg.x + bb.x);
    o4.y = f2bf((v.y - mean) * inv * gg.y + bb.y);
    o4.z = f2bf((v.z - mean) * inv * gg.z + bb.z);
    o4.w = f2bf((v.w - mean) * inv * gg.w + bb.w);
    ((ushort4*)(out + (size_t)row * DD))[tid] = o4;
}

// ---------------------------------------------------------------- weight transpose+convert
// W fp32 [K][N] -> Wt bf16 [N][K]
__global__ __launch_bounds__(256) void transpose_bf16(
    const float* __restrict__ W, unsigned short* __restrict__ Wt, int K, int N)
{
    __shared__ float tile[32][33];
    int n0 = blockIdx.x * 32, k0 = blockIdx.y * 32;
    int tx = threadIdx.x & 31, ty = threadIdx.x >> 5;   // ty 0..7
    #pragma unroll
    for (int i = 0; i < 4; i++)
        tile[ty + i*8][tx] = W[(size_t)(k0 + ty + i*8) * N + n0 + tx];
    __syncthreads();
    #pragma unroll
    for (int i = 0; i < 4; i++)
        Wt[(size_t)(n0 + ty + i*8) * K + k0 + tx] = f2bf(tile[tx][ty + i*8]);
}

// ---------------------------------------------------------------- MFMA GEMM (m97 structure)
// C[M,N] = act(A[M,K] @ Bt[N,K]^T + bias) (+ res). 128x128 tile, BK=32, 256 thr.
template<int ACT, int RES, int OUTBF>
__global__ __launch_bounds__(256) void mfma_gemm(
    const unsigned short* __restrict__ A, const unsigned short* __restrict__ Bt,
    const float* __restrict__ bias, const float* __restrict__ res,
    void* __restrict__ Cv, int M, int N, int K)
{
    __shared__ unsigned short As[128*32];
    __shared__ unsigned short Bs[128*32];
    const int tid = threadIdx.x;
    const int wave = tid >> 6, lane = tid & 63;
    const int quad = lane >> 4, lc = lane & 15;
    const int m0 = blockIdx.y * 128, n0 = blockIdx.x * 128;

    const unsigned short* Ag = A  + (size_t)(m0 + wave*32 + (lane>>2)) * K + (lane&3)*8;
    const unsigned short* Bg = Bt + (size_t)(n0 + wave*32 + (lane>>2)) * K + (lane&3)*8;
    unsigned short* Al = &As[wave*32*32];
    unsigned short* Bl = &Bs[wave*32*32];

    const int wm = (wave & 1) * 64, wn = (wave >> 1) * 64;

    floatx4 acc[4][4];
    #pragma unroll
    for (int i = 0; i < 4; i++)
        #pragma unroll
        for (int j = 0; j < 4; j++) acc[i][j] = (floatx4)0.0f;

    for (int k0 = 0; k0 < K; k0 += 32) {
        __syncthreads();
        g2l16(Ag + k0, Al);
        g2l16(Ag + k0 + (size_t)16*K, Al + 16*32);
        g2l16(Bg + k0, Bl);
        g2l16(Bg + k0 + (size_t)16*K, Bl + 16*32);
        __syncthreads();
        bf16x8 af[4], bf[4];
        #pragma unroll
        for (int i = 0; i < 4; i++)
            af[i] = *(const bf16x8*)&As[(wm + i*16 + lc)*32 + quad*8];
        #pragma unroll
        for (int j = 0; j < 4; j++)
            bf[j] = *(const bf16x8*)&Bs[(wn + j*16 + lc)*32 + quad*8];
        #pragma unroll
        for (int i = 0; i < 4; i++)
            #pragma unroll
            for (int j = 0; j < 4; j++)
                acc[i][j] = __builtin_amdgcn_mfma_f32_16x16x32_bf16(af[i], bf[j], acc[i][j], 0, 0, 0);
    }

    #pragma unroll
    for (int j = 0; j < 4; j++) {
        int n = n0 + wn + j*16 + lc;
        float bv = bias ? bias[n] : 0.0f;
        #pragma unroll
        for (int i = 0; i < 4; i++) {
            int mbase = m0 + wm + i*16 + quad*4;
            #pragma unroll
            for (int r = 0; r < 4; r++) {
                int m = mbase + r;
                float v = acc[i][j][r] + bv;
                if (ACT) v = 0.5f * v * (1.0f + erff(v * 0.70710678118654752f));
                if (RES) v += res[(size_t)m * N + n];
                if (OUTBF) ((unsigned short*)Cv)[(size_t)m * N + n] = f2bf(v);
                else       ((float*)Cv)[(size_t)m * N + n] = v;
            }
        }
    }
}

// ---------------------------------------------------------------- flash attention (bf16 MFMA)
// grid (T/64, B*H). block 256 = 4 waves. 64 Q rows/block, online softmax over 16 key tiles.
#define LSTR 88   // LDS row stride (elements): 16B-aligned, conflict-light
__global__ __launch_bounds__(256) void attn_mfma(
    const unsigned short* __restrict__ q, const unsigned short* __restrict__ k,
    const unsigned short* __restrict__ v, unsigned short* __restrict__ y)
{
    __shared__ unsigned short Qs[64*LSTR];
    __shared__ unsigned short Ks[64*LSTR];   // reused as V^T [dh][s]
    __shared__ unsigned short Ps[64*LSTR];
    const int tid = threadIdx.x, wave = tid >> 6, lane = tid & 63;
    const int quad = lane >> 4, lc = lane & 15;
    const int t0 = blockIdx.x * 64;
    const int b = blockIdx.y >> 4, h = blockIdx.y & 15;

    const size_t rowbase = (size_t)b * TT;
    const int sr = tid >> 2, sc = (tid & 3) * 16;   // staging: row, 16-el col chunk

    {   // stage Q [64 t][64 dh]
        const unsigned short* src = q + (rowbase + t0 + sr) * DD + h*DHH + sc;
        *(uint4*)&Qs[sr*LSTR + sc]     = *(const uint4*)src;
        *(uint4*)&Qs[sr*LSTR + sc + 8] = *(const uint4*)(src + 8);
    }

    float m_r[4], l_r[4];
    floatx4 o_acc[4];
    #pragma unroll
    for (int r = 0; r < 4; r++) { m_r[r] = -1e30f; l_r[r] = 0.0f; }
    #pragma unroll
    for (int f = 0; f < 4; f++) o_acc[f] = (floatx4)0.0f;

    for (int s0 = 0; s0 < TT; s0 += 64) {
        __syncthreads();   // prev PV done with Ks/Ps; Q staged (first iter)
        {   // stage K [64 s][64 dh]
            const unsigned short* src = k + (rowbase + s0 + sr) * DD + h*DHH + sc;
            *(uint4*)&Ks[sr*LSTR + sc]     = *(const uint4*)src;
            *(uint4*)&Ks[sr*LSTR + sc + 8] = *(const uint4*)(src + 8);
        }
        __syncthreads();

        // S[16q x 64s] per wave = Q @ K^T
        floatx4 s[4];
        #pragma unroll
        for (int f = 0; f < 4; f++) s[f] = (floatx4)0.0f;
        #pragma unroll
        for (int c = 0; c < 2; c++) {
            bf16x8 aq = *(const bf16x8*)&Qs[(wave*16 + lc)*LSTR + c*32 + quad*8];
            #pragma unroll
            for (int f = 0; f < 4; f++) {
                bf16x8 bk = *(const bf16x8*)&Ks[(f*16 + lc)*LSTR + c*32 + quad*8];
                s[f] = __builtin_amdgcn_mfma_f32_16x16x32_bf16(aq, bk, s[f], 0, 0, 0);
            }
        }

        // online softmax: rows = quad*4 + r, cols = f*16 + lc (reduce over 16 lanes)
        #pragma unroll
        for (int r = 0; r < 4; r++) {
            float mt = fmaxf(fmaxf(s[0][r], s[1][r]), fmaxf(s[2][r], s[3][r])) * 0.125f;
            #pragma unroll
            for (int d = 1; d < 16; d <<= 1) mt = fmaxf(mt, __shfl_xor(mt, d, 64));
            float mn = fmaxf(m_r[r], mt);
            float alpha = __expf(m_r[r] - mn);
            m_r[r] = mn;
            float rs = 0.0f;
            #pragma unroll
            for (int f = 0; f < 4; f++) {
                float p = __expf(s[f][r] * 0.125f - mn);
                s[f][r] = p;
                rs += p;
            }
            #pragma unroll
            for (int d = 1; d < 16; d <<= 1) rs += __shfl_xor(rs, d, 64);
            l_r[r] = l_r[r] * alpha + rs;
            #pragma unroll
            for (int f = 0; f < 4; f++) o_acc[f][r] *= alpha;
        }

        // P -> LDS (C-layout to A-layout round trip)
        #pragma unroll
        for (int f = 0; f < 4; f++)
            #pragma unroll
            for (int r = 0; r < 4; r++)
                Ps[(wave*16 + quad*4 + r)*LSTR + f*16 + lc] = f2bf(s[f][r]);

        __syncthreads();   // Ps visible; all waves done reading Ks
        {   // stage V^T [64 dh][64 s] into Ks
            const unsigned short* src = v + (rowbase + s0 + sr) * DD + h*DHH + sc;
            uint4 v0 = *(const uint4*)src;
            uint4 v1 = *(const uint4*)(src + 8);
            unsigned short tmp[16];
            *(uint4*)&tmp[0] = v0;
            *(uint4*)&tmp[8] = v1;
            #pragma unroll
            for (int e = 0; e < 16; e++)
                Ks[(sc + e)*LSTR + sr] = tmp[e];
        }
        __syncthreads();

        // O[16q x 64dh] += P @ V
        #pragma unroll
        for (int c = 0; c < 2; c++) {
            bf16x8 ap = *(const bf16x8*)&Ps[(wave*16 + lc)*LSTR + c*32 + quad*8];
            #pragma unroll
            for (int f = 0; f < 4; f++) {
                bf16x8 bv = *(const bf16x8*)&Ks[(f*16 + lc)*LSTR + c*32 + quad*8];
                o_acc[f] = __builtin_amdgcn_mfma_f32_16x16x32_bf16(ap, bv, o_acc[f], 0, 0, 0);
            }
        }
    }

    unsigned short* yg = y + (rowbase + t0) * DD + h*DHH;
    #pragma unroll
    for (int f = 0; f < 4; f++)
        #pragma unroll
        for (int r = 0; r < 4; r++)
            yg[(size_t)(wave*16 + quad*4 + r) * DD + f*16 + lc] = f2bf(o_acc[f][r] / l_r[r]);
}

// ---------------------------------------------------------------- launch
extern "C" void kernel_launch(void* const* d_in, const int* in_sizes, int n_in,
                              void* d_out, int out_size, void* d_ws, size_t ws_size,
                              hipStream_t stream)
{
    const float* seq    = (const float*)d_in[0];
    const float* pos    = (const float*)d_in[1];
    const float* ln1_g  = (const float*)d_in[2];
    const float* ln1_b  = (const float*)d_in[3];
    const float* wq     = (const float*)d_in[4];
    const float* bq     = (const float*)d_in[5];
    const float* wk     = (const float*)d_in[6];
    const float* bk     = (const float*)d_in[7];
    const float* wv     = (const float*)d_in[8];
    const float* bv     = (const float*)d_in[9];
    const float* wo     = (const float*)d_in[10];
    const float* bo     = (const float*)d_in[11];
    const float* ln2_g  = (const float*)d_in[12];
    const float* ln2_b  = (const float*)d_in[13];
    const float* w1     = (const float*)d_in[14];
    const float* b1     = (const float*)d_in[15];
    const float* w2     = (const float*)d_in[16];
    const float* b2     = (const float*)d_in[17];
    const float* lnf_g  = (const float*)d_in[18];
    const float* lnf_b  = (const float*)d_in[19];
    const float* w_head = (const float*)d_in[20];
    float* out = (float*)d_out;

    const size_t MSZ = (size_t)MM * DD;          // 4M elements
    float* x            = (float*)d_ws;                 // 16 MB fp32
    unsigned short* h   = (unsigned short*)(x + MSZ);   // 8 MB bf16
    unsigned short* qb  = h  + MSZ;
    unsigned short* kb  = qb + MSZ;
    unsigned short* vb  = kb + MSZ;
    unsigned short* ub  = vb + MSZ;                     // [4096][4096] bf16, 32 MB
    unsigned short* wt  = ub + (size_t)MM * 4 * DD;     // 12M el transposed weights, 24 MB
    unsigned short* wtq = wt;
    unsigned short* wtk = wt + (size_t)DD*DD;
    unsigned short* wtv = wt + (size_t)2*DD*DD;
    unsigned short* wto = wt + (size_t)3*DD*DD;
    unsigned short* wt1 = wt + (size_t)4*DD*DD;         // [4096][1024]
    unsigned short* wt2 = wt + (size_t)8*DD*DD;         // [1024][4096]

    dim3 blk(256);
    dim3 g1(8, 32);     // GEMM N=1024
    dim3 g4(32, 32);    // GEMM N=4096
    dim3 tsq(32, 32);   // transpose 1024x1024
    dim3 t14(128, 32);  // w1: K=1024,N=4096
    dim3 t41(32, 128);  // w2: K=4096,N=1024
    dim3 ag(16, 64);    // attention

    add_pos_kernel<<<4096, blk, 0, stream>>>(seq, pos, x);

    for (int l = 0; l < LL; l++) {
        const size_t wofs  = (size_t)l * DD * DD;
        const size_t bofs  = (size_t)l * DD;
        const size_t w1ofs = (size_t)l * DD * 4 * DD;
        const size_t b1ofs = (size_t)l * 4 * DD;

        transpose_bf16<<<tsq, blk, 0, stream>>>(wq + wofs, wtq, DD, DD);
        transpose_bf16<<<tsq, blk, 0, stream>>>(wk + wofs, wtk, DD, DD);
        transpose_bf16<<<tsq, blk, 0, stream>>>(wv + wofs, wtv, DD, DD);
        transpose_bf16<<<tsq, blk, 0, stream>>>(wo + wofs, wto, DD, DD);
        transpose_bf16<<<t14, blk, 0, stream>>>(w1 + w1ofs, wt1, DD, 4*DD);
        transpose_bf16<<<t41, blk, 0, stream>>>(w2 + w1ofs, wt2, 4*DD, DD);

        ln_kernel<<<MM, blk, 0, stream>>>(x, ln1_g + bofs, ln1_b + bofs, h);
        mfma_gemm<0,0,1><<<g1, blk, 0, stream>>>(h, wtq, bq + bofs, nullptr, qb, MM, DD, DD);
        mfma_gemm<0,0,1><<<g1, blk, 0, stream>>>(h, wtk, bk + bofs, nullptr, kb, MM, DD, DD);
        mfma_gemm<0,0,1><<<g1, blk, 0, stream>>>(h, wtv, bv + bofs, nullptr, vb, MM, DD, DD);
        attn_mfma<<<ag, blk, 0, stream>>>(qb, kb, vb, h);
        mfma_gemm<0,1,0><<<g1, blk, 0, stream>>>(h, wto, bo + bofs, x, x, MM, DD, DD);
        ln_kernel<<<MM, blk, 0, stream>>>(x, ln2_g + bofs, ln2_b + bofs, h);
        mfma_gemm<1,0,1><<<g4, blk, 0, stream>>>(h, wt1, b1 + b1ofs, nullptr, ub, MM, 4*DD, DD);
        mfma_gemm<0,1,0><<<g1, blk, 0, stream>>>(ub, wt2, b2 + bofs, x, x, MM, DD, 4*DD);
    }

    ln_kernel<<<MM, blk, 0, stream>>>(x, lnf_g, lnf_b, h);
    transpose_bf16<<<tsq, blk, 0, stream>>>(w_head, wtq, DD, DD);
    mfma_gemm<0,0,0><<<g1, blk, 0, stream>>>(h, wtq, nullptr, nullptr, out, MM, DD, DD);
}

// Round 3
// 2192.658 us; speedup vs baseline: 15.2860x; 1.1759x over previous
//
#include <hip/hip_runtime.h>
#include <math.h>

#define BB 4
#define TT 1024
#define DD 1024
#define HH 16
#define LL 6
#define DHH 64
#define MM (BB*TT)   // 4096
#define QKVLD 3072

typedef short bf16x8 __attribute__((ext_vector_type(8)));
typedef float floatx4 __attribute__((ext_vector_type(4)));

#define AS1 __attribute__((address_space(1)))
#define AS3 __attribute__((address_space(3)))

__device__ __forceinline__ void g2l16(const void* g, void* l) {
    __builtin_amdgcn_global_load_lds((const AS1 unsigned int*)g,
                                     (AS3 unsigned int*)l, 16, 0, 0);
}

__device__ __forceinline__ unsigned short f2bf(float f) {
    unsigned u = __builtin_bit_cast(unsigned, f);
    u += 0x7fffu + ((u >> 16) & 1u);
    return (unsigned short)(u >> 16);
}

// ---------------------------------------------------------------- add pos (fp32 out)
__global__ __launch_bounds__(256) void add_pos_kernel(
    const float* __restrict__ seq, const float* __restrict__ pos, float* __restrict__ x)
{
    int i = blockIdx.x * 256 + threadIdx.x;
    const int TD4 = TT * DD / 4;
    float4 s = ((const float4*)seq)[i];
    float4 p = ((const float4*)pos)[i & (TD4 - 1)];
    ((float4*)x)[i] = make_float4(s.x + p.x, s.y + p.y, s.z + p.z, s.w + p.w);
}

// ---------------------------------------------------------------- bias concat (all layers)
__global__ __launch_bounds__(256) void concat_bias_kernel(
    const float* __restrict__ bq, const float* __restrict__ bk,
    const float* __restrict__ bv, float* __restrict__ bqkv)
{
    int i = blockIdx.x * 256 + threadIdx.x;     // LL*3072 total
    int l = i / QKVLD, j = i - l * QKVLD;
    float v;
    if (j < DD)            v = bq[l*DD + j];
    else if (j < 2*DD)     v = bk[l*DD + j - DD];
    else                   v = bv[l*DD + j - 2*DD];
    bqkv[i] = v;
}

// ---------------------------------------------------------------- layernorm (fp32 in, bf16 out)
__global__ __launch_bounds__(256) void ln_kernel(
    const float* __restrict__ x, const float* __restrict__ g,
    const float* __restrict__ b, unsigned short* __restrict__ out)
{
    __shared__ float red[8];
    int row = blockIdx.x;
    int tid = threadIdx.x;
    const float4* xr = (const float4*)(x + (size_t)row * DD);
    float4 v = xr[tid];
    float s  = v.x + v.y + v.z + v.w;
    float ss = v.x*v.x + v.y*v.y + v.z*v.z + v.w*v.w;
    #pragma unroll
    for (int o = 32; o > 0; o >>= 1) {
        s  += __shfl_down(s,  o, 64);
        ss += __shfl_down(ss, o, 64);
    }
    int wid = tid >> 6, lid = tid & 63;
    if (lid == 0) { red[wid] = s; red[4 + wid] = ss; }
    __syncthreads();
    float sum  = red[0] + red[1] + red[2] + red[3];
    float sums = red[4] + red[5] + red[6] + red[7];
    float mean = sum * (1.0f / DD);
    float var  = sums * (1.0f / DD) - mean * mean;
    float inv  = rsqrtf(var + 1e-5f);
    float4 gg = ((const float4*)g)[tid];
    float4 bb = ((const float4*)b)[tid];
    ushort4 o4;
    o4.x = f2bf((v.x - mean) * inv * gg.x + bb.x);
    o4.y = f2bf((v.y - mean) * inv * gg.y + bb.y);
    o4.z = f2bf((v.z - mean) * inv * gg.z + bb.z);
    o4.w = f2bf((v.w - mean) * inv * gg.w + bb.w);
    ((ushort4*)(out + (size_t)row * DD))[tid] = o4;
}

// ---------------------------------------------------------------- weight transpose+convert
// W fp32 [K][N] -> Wt bf16 [N][K]
__global__ __launch_bounds__(256) void transpose_bf16(
    const float* __restrict__ W, unsigned short* __restrict__ Wt, int K, int N)
{
    __shared__ float tile[32][33];
    int n0 = blockIdx.x * 32, k0 = blockIdx.y * 32;
    int tx = threadIdx.x & 31, ty = threadIdx.x >> 5;   // ty 0..7
    #pragma unroll
    for (int i = 0; i < 4; i++)
        tile[ty + i*8][tx] = W[(size_t)(k0 + ty + i*8) * N + n0 + tx];
    __syncthreads();
    #pragma unroll
    for (int i = 0; i < 4; i++)
        Wt[(size_t)(n0 + ty + i*8) * K + k0 + tx] = f2bf(tile[tx][ty + i*8]);
}

// ---------------------------------------------------------------- MFMA GEMM
// C[M,N] = act(A[M,K] @ Bt[N,K]^T + bias) (+ res). 128x128 tile, BK=64 (2x32 buf),
// 256 thr, XCD-aware 1D grid swizzle. M fixed = 4096 (32 m-blocks).
template<int ACT, int RES, int OUTBF>
__global__ __launch_bounds__(256) void mfma_gemm(
    const unsigned short* __restrict__ A, const unsigned short* __restrict__ Bt,
    const float* __restrict__ bias, const float* __restrict__ res,
    void* __restrict__ Cv, int M, int N, int K)
{
    __shared__ unsigned short As0[128*32], As1[128*32];
    __shared__ unsigned short Bs0[128*32], Bs1[128*32];
    const int tid = threadIdx.x;
    const int wave = tid >> 6, lane = tid & 63;
    const int quad = lane >> 4, lc = lane & 15;

    // XCD swizzle: xcd gets m-band [xcd*4, xcd*4+4), m-fastest within XCD
    const int bid = blockIdx.x;
    const int xcd = bid & 7;
    const int j = bid >> 3;
    const int m0 = (xcd * 4 + (j & 3)) << 7;
    const int n0 = (j >> 2) << 7;

    const unsigned short* Ag = A  + (size_t)(m0 + wave*32 + (lane>>2)) * K + (lane&3)*8;
    const unsigned short* Bg = Bt + (size_t)(n0 + wave*32 + (lane>>2)) * K + (lane&3)*8;
    unsigned short* Al0 = &As0[wave*32*32];
    unsigned short* Bl0 = &Bs0[wave*32*32];
    unsigned short* Al1 = &As1[wave*32*32];
    unsigned short* Bl1 = &Bs1[wave*32*32];

    const int wm = (wave & 1) * 64, wn = (wave >> 1) * 64;

    floatx4 acc[4][4];
    #pragma unroll
    for (int i = 0; i < 4; i++)
        #pragma unroll
        for (int jj = 0; jj < 4; jj++) acc[i][jj] = (floatx4)0.0f;

    for (int k0 = 0; k0 < K; k0 += 64) {
        __syncthreads();
        g2l16(Ag + k0,                     Al0);
        g2l16(Ag + k0 + (size_t)16*K,      Al0 + 16*32);
        g2l16(Bg + k0,                     Bl0);
        g2l16(Bg + k0 + (size_t)16*K,      Bl0 + 16*32);
        g2l16(Ag + k0 + 32,                Al1);
        g2l16(Ag + k0 + 32 + (size_t)16*K, Al1 + 16*32);
        g2l16(Bg + k0 + 32,                Bl1);
        g2l16(Bg + k0 + 32 + (size_t)16*K, Bl1 + 16*32);
        __syncthreads();
        #pragma unroll
        for (int hh = 0; hh < 2; hh++) {
            const unsigned short* Asx = hh ? As1 : As0;
            const unsigned short* Bsx = hh ? Bs1 : Bs0;
            bf16x8 af[4], bf[4];
            #pragma unroll
            for (int i = 0; i < 4; i++)
                af[i] = *(const bf16x8*)&Asx[(wm + i*16 + lc)*32 + quad*8];
            #pragma unroll
            for (int jj = 0; jj < 4; jj++)
                bf[jj] = *(const bf16x8*)&Bsx[(wn + jj*16 + lc)*32 + quad*8];
            #pragma unroll
            for (int i = 0; i < 4; i++)
                #pragma unroll
                for (int jj = 0; jj < 4; jj++)
                    acc[i][jj] = __builtin_amdgcn_mfma_f32_16x16x32_bf16(af[i], bf[jj], acc[i][jj], 0, 0, 0);
        }
    }

    #pragma unroll
    for (int jj = 0; jj < 4; jj++) {
        int n = n0 + wn + jj*16 + lc;
        float bv = bias ? bias[n] : 0.0f;
        #pragma unroll
        for (int i = 0; i < 4; i++) {
            int mbase = m0 + wm + i*16 + quad*4;
            #pragma unroll
            for (int r = 0; r < 4; r++) {
                int m = mbase + r;
                float v = acc[i][jj][r] + bv;
                if (ACT) v = 0.5f * v * (1.0f + erff(v * 0.70710678118654752f));
                if (RES) v += res[(size_t)m * N + n];
                if (OUTBF) ((unsigned short*)Cv)[(size_t)m * N + n] = f2bf(v);
                else       ((float*)Cv)[(size_t)m * N + n] = v;
            }
        }
    }
}

// ---------------------------------------------------------------- flash attention (bf16 MFMA)
// grid (T/64, B*H). block 256 = 4 waves. qkv packed [B*T][3072]: q|k|v.
#define LSTR 88
__global__ __launch_bounds__(256) void attn_mfma(
    const unsigned short* __restrict__ qkv, unsigned short* __restrict__ y)
{
    __shared__ unsigned short Qs[64*LSTR];
    __shared__ unsigned short Ks[64*LSTR];   // reused as V^T [dh][s]
    __shared__ unsigned short Ps[64*LSTR];
    const int tid = threadIdx.x, wave = tid >> 6, lane = tid & 63;
    const int quad = lane >> 4, lc = lane & 15;
    const int t0 = blockIdx.x * 64;
    const int b = blockIdx.y >> 4, h = blockIdx.y & 15;

    const unsigned short* q = qkv;
    const unsigned short* k = qkv + DD;
    const unsigned short* v = qkv + 2*DD;

    const size_t rowbase = (size_t)b * TT;
    const int sr = tid >> 2, sc = (tid & 3) * 16;

    {   // stage Q [64 t][64 dh]
        const unsigned short* src = q + (rowbase + t0 + sr) * QKVLD + h*DHH + sc;
        *(uint4*)&Qs[sr*LSTR + sc]     = *(const uint4*)src;
        *(uint4*)&Qs[sr*LSTR + sc + 8] = *(const uint4*)(src + 8);
    }

    float m_r[4], l_r[4];
    floatx4 o_acc[4];
    #pragma unroll
    for (int r = 0; r < 4; r++) { m_r[r] = -1e30f; l_r[r] = 0.0f; }
    #pragma unroll
    for (int f = 0; f < 4; f++) o_acc[f] = (floatx4)0.0f;

    for (int s0 = 0; s0 < TT; s0 += 64) {
        __syncthreads();
        {   // stage K [64 s][64 dh]
            const unsigned short* src = k + (rowbase + s0 + sr) * QKVLD + h*DHH + sc;
            *(uint4*)&Ks[sr*LSTR + sc]     = *(const uint4*)src;
            *(uint4*)&Ks[sr*LSTR + sc + 8] = *(const uint4*)(src + 8);
        }
        __syncthreads();

        floatx4 s[4];
        #pragma unroll
        for (int f = 0; f < 4; f++) s[f] = (floatx4)0.0f;
        #pragma unroll
        for (int c = 0; c < 2; c++) {
            bf16x8 aq = *(const bf16x8*)&Qs[(wave*16 + lc)*LSTR + c*32 + quad*8];
            #pragma unroll
            for (int f = 0; f < 4; f++) {
                bf16x8 bk = *(const bf16x8*)&Ks[(f*16 + lc)*LSTR + c*32 + quad*8];
                s[f] = __builtin_amdgcn_mfma_f32_16x16x32_bf16(aq, bk, s[f], 0, 0, 0);
            }
        }

        #pragma unroll
        for (int r = 0; r < 4; r++) {
            float mt = fmaxf(fmaxf(s[0][r], s[1][r]), fmaxf(s[2][r], s[3][r])) * 0.125f;
            #pragma unroll
            for (int d = 1; d < 16; d <<= 1) mt = fmaxf(mt, __shfl_xor(mt, d, 64));
            float mn = fmaxf(m_r[r], mt);
            float alpha = __expf(m_r[r] - mn);
            m_r[r] = mn;
            float rs = 0.0f;
            #pragma unroll
            for (int f = 0; f < 4; f++) {
                float p = __expf(s[f][r] * 0.125f - mn);
                s[f][r] = p;
                rs += p;
            }
            #pragma unroll
            for (int d = 1; d < 16; d <<= 1) rs += __shfl_xor(rs, d, 64);
            l_r[r] = l_r[r] * alpha + rs;
            #pragma unroll
            for (int f = 0; f < 4; f++) o_acc[f][r] *= alpha;
        }

        #pragma unroll
        for (int f = 0; f < 4; f++)
            #pragma unroll
            for (int r = 0; r < 4; r++)
                Ps[(wave*16 + quad*4 + r)*LSTR + f*16 + lc] = f2bf(s[f][r]);

        __syncthreads();
        {   // stage V^T [64 dh][64 s] into Ks
            const unsigned short* src = v + (rowbase + s0 + sr) * QKVLD + h*DHH + sc;
            uint4 v0 = *(const uint4*)src;
            uint4 v1 = *(const uint4*)(src + 8);
            unsigned short tmp[16];
            *(uint4*)&tmp[0] = v0;
            *(uint4*)&tmp[8] = v1;
            #pragma unroll
            for (int e = 0; e < 16; e++)
                Ks[(sc + e)*LSTR + sr] = tmp[e];
        }
        __syncthreads();

        #pragma unroll
        for (int c = 0; c < 2; c++) {
            bf16x8 ap = *(const bf16x8*)&Ps[(wave*16 + lc)*LSTR + c*32 + quad*8];
            #pragma unroll
            for (int f = 0; f < 4; f++) {
                bf16x8 bv = *(const bf16x8*)&Ks[(f*16 + lc)*LSTR + c*32 + quad*8];
                o_acc[f] = __builtin_amdgcn_mfma_f32_16x16x32_bf16(ap, bv, o_acc[f], 0, 0, 0);
            }
        }
    }

    unsigned short* yg = y + (rowbase + t0) * DD + h*DHH;
    #pragma unroll
    for (int f = 0; f < 4; f++)
        #pragma unroll
        for (int r = 0; r < 4; r++)
            yg[(size_t)(wave*16 + quad*4 + r) * DD + f*16 + lc] = f2bf(o_acc[f][r] / l_r[r]);
}

// ---------------------------------------------------------------- launch
extern "C" void kernel_launch(void* const* d_in, const int* in_sizes, int n_in,
                              void* d_out, int out_size, void* d_ws, size_t ws_size,
                              hipStream_t stream)
{
    const float* seq    = (const float*)d_in[0];
    const float* pos    = (const float*)d_in[1];
    const float* ln1_g  = (const float*)d_in[2];
    const float* ln1_b  = (const float*)d_in[3];
    const float* wq     = (const float*)d_in[4];
    const float* bq     = (const float*)d_in[5];
    const float* wk     = (const float*)d_in[6];
    const float* bk     = (const float*)d_in[7];
    const float* wv     = (const float*)d_in[8];
    const float* bv     = (const float*)d_in[9];
    const float* wo     = (const float*)d_in[10];
    const float* bo     = (const float*)d_in[11];
    const float* ln2_g  = (const float*)d_in[12];
    const float* ln2_b  = (const float*)d_in[13];
    const float* w1     = (const float*)d_in[14];
    const float* b1     = (const float*)d_in[15];
    const float* w2     = (const float*)d_in[16];
    const float* b2     = (const float*)d_in[17];
    const float* lnf_g  = (const float*)d_in[18];
    const float* lnf_b  = (const float*)d_in[19];
    const float* w_head = (const float*)d_in[20];
    float* out = (float*)d_out;

    const size_t MSZ = (size_t)MM * DD;
    float* x            = (float*)d_ws;                 // 16 MB fp32
    unsigned short* h   = (unsigned short*)(x + MSZ);   // 8 MB bf16
    unsigned short* qkv = h + MSZ;                      // [4096][3072] bf16, 24 MB
    unsigned short* ub  = qkv + (size_t)MM * QKVLD;     // [4096][4096] bf16, 32 MB
    unsigned short* wt  = ub + (size_t)MM * 4 * DD;     // 12M el, 24 MB
    unsigned short* wtq = wt;                           // [3072][1024] = q|k|v rows
    unsigned short* wtk = wt + (size_t)DD*DD;
    unsigned short* wtv = wt + (size_t)2*DD*DD;
    unsigned short* wto = wt + (size_t)3*DD*DD;
    unsigned short* wt1 = wt + (size_t)4*DD*DD;         // [4096][1024]
    unsigned short* wt2 = wt + (size_t)8*DD*DD;         // [1024][4096]
    float* bqkv         = (float*)(wt + (size_t)12*DD*DD);  // [L][3072] fp32

    dim3 blk(256);
    dim3 g1(32*8);      // N=1024: 256 blocks (1D swizzled)
    dim3 gq(32*24);     // N=3072: 768 blocks
    dim3 g4(32*32);     // N=4096: 1024 blocks
    dim3 tsq(32, 32);
    dim3 t14(128, 32);
    dim3 t41(32, 128);
    dim3 ag(16, 64);

    add_pos_kernel<<<4096, blk, 0, stream>>>(seq, pos, x);
    concat_bias_kernel<<<LL*QKVLD/256, blk, 0, stream>>>(bq, bk, bv, bqkv);

    for (int l = 0; l < LL; l++) {
        const size_t wofs  = (size_t)l * DD * DD;
        const size_t bofs  = (size_t)l * DD;
        const size_t w1ofs = (size_t)l * DD * 4 * DD;
        const size_t b1ofs = (size_t)l * 4 * DD;

        transpose_bf16<<<tsq, blk, 0, stream>>>(wq + wofs, wtq, DD, DD);
        transpose_bf16<<<tsq, blk, 0, stream>>>(wk + wofs, wtk, DD, DD);
        transpose_bf16<<<tsq, blk, 0, stream>>>(wv + wofs, wtv, DD, DD);
        transpose_bf16<<<tsq, blk, 0, stream>>>(wo + wofs, wto, DD, DD);
        transpose_bf16<<<t14, blk, 0, stream>>>(w1 + w1ofs, wt1, DD, 4*DD);
        transpose_bf16<<<t41, blk, 0, stream>>>(w2 + w1ofs, wt2, 4*DD, DD);

        ln_kernel<<<MM, blk, 0, stream>>>(x, ln1_g + bofs, ln1_b + bofs, h);
        mfma_gemm<0,0,1><<<gq, blk, 0, stream>>>(h, wt, bqkv + (size_t)l*QKVLD, nullptr, qkv, MM, QKVLD, DD);
        attn_mfma<<<ag, blk, 0, stream>>>(qkv, h);
        mfma_gemm<0,1,0><<<g1, blk, 0, stream>>>(h, wto, bo + bofs, x, x, MM, DD, DD);
        ln_kernel<<<MM, blk, 0, stream>>>(x, ln2_g + bofs, ln2_b + bofs, h);
        mfma_gemm<1,0,1><<<g4, blk, 0, stream>>>(h, wt1, b1 + b1ofs, nullptr, ub, MM, 4*DD, DD);
        mfma_gemm<0,1,0><<<g1, blk, 0, stream>>>(ub, wt2, b2 + bofs, x, x, MM, DD, 4*DD);
    }

    ln_kernel<<<MM, blk, 0, stream>>>(x, lnf_g, lnf_b, h);
    transpose_bf16<<<tsq, blk, 0, stream>>>(w_head, wtq, DD, DD);
    mfma_gemm<0,0,0><<<g1, blk, 0, stream>>>(h, wtq, nullptr, nullptr, out, MM, DD, DD);
}

// Round 4
// 2003.725 us; speedup vs baseline: 16.7273x; 1.0943x over previous
//
#include <hip/hip_runtime.h>
#include <math.h>

#define BB 4
#define TT 1024
#define DD 1024
#define HH 16
#define LL 6
#define DHH 64
#define MM (BB*TT)   // 4096
#define QKVLD 3072

typedef short bf16x8 __attribute__((ext_vector_type(8)));
typedef float floatx4 __attribute__((ext_vector_type(4)));

__device__ __forceinline__ unsigned short f2bf(float f) {
    unsigned u = __builtin_bit_cast(unsigned, f);
    u += 0x7fffu + ((u >> 16) & 1u);
    return (unsigned short)(u >> 16);
}

// ---------------------------------------------------------------- add pos (fp32 out)
__global__ __launch_bounds__(256) void add_pos_kernel(
    const float* __restrict__ seq, const float* __restrict__ pos, float* __restrict__ x)
{
    int i = blockIdx.x * 256 + threadIdx.x;
    const int TD4 = TT * DD / 4;
    float4 s = ((const float4*)seq)[i];
    float4 p = ((const float4*)pos)[i & (TD4 - 1)];
    ((float4*)x)[i] = make_float4(s.x + p.x, s.y + p.y, s.z + p.z, s.w + p.w);
}

// ---------------------------------------------------------------- bias concat (all layers)
__global__ __launch_bounds__(256) void concat_bias_kernel(
    const float* __restrict__ bq, const float* __restrict__ bk,
    const float* __restrict__ bv, float* __restrict__ bqkv)
{
    int i = blockIdx.x * 256 + threadIdx.x;     // LL*3072 total
    int l = i / QKVLD, j = i - l * QKVLD;
    float v;
    if (j < DD)            v = bq[l*DD + j];
    else if (j < 2*DD)     v = bk[l*DD + j - DD];
    else                   v = bv[l*DD + j - 2*DD];
    bqkv[i] = v;
}

// ---------------------------------------------------------------- layernorm (fp32 in, bf16 out)
__global__ __launch_bounds__(256) void ln_kernel(
    const float* __restrict__ x, const float* __restrict__ g,
    const float* __restrict__ b, unsigned short* __restrict__ out)
{
    __shared__ float red[8];
    int row = blockIdx.x;
    int tid = threadIdx.x;
    const float4* xr = (const float4*)(x + (size_t)row * DD);
    float4 v = xr[tid];
    float s  = v.x + v.y + v.z + v.w;
    float ss = v.x*v.x + v.y*v.y + v.z*v.z + v.w*v.w;
    #pragma unroll
    for (int o = 32; o > 0; o >>= 1) {
        s  += __shfl_down(s,  o, 64);
        ss += __shfl_down(ss, o, 64);
    }
    int wid = tid >> 6, lid = tid & 63;
    if (lid == 0) { red[wid] = s; red[4 + wid] = ss; }
    __syncthreads();
    float sum  = red[0] + red[1] + red[2] + red[3];
    float sums = red[4] + red[5] + red[6] + red[7];
    float mean = sum * (1.0f / DD);
    float var  = sums * (1.0f / DD) - mean * mean;
    float inv  = rsqrtf(var + 1e-5f);
    float4 gg = ((const float4*)g)[tid];
    float4 bb = ((const float4*)b)[tid];
    ushort4 o4;
    o4.x = f2bf((v.x - mean) * inv * gg.x + bb.x);
    o4.y = f2bf((v.y - mean) * inv * gg.y + bb.y);
    o4.z = f2bf((v.z - mean) * inv * gg.z + bb.z);
    o4.w = f2bf((v.w - mean) * inv * gg.w + bb.w);
    ((ushort4*)(out + (size_t)row * DD))[tid] = o4;
}

// ---------------------------------------------------------------- per-layer transpose
// All 6 weight matrices of one layer -> wt (bf16, [N][K] each), single dispatch.
// wt layout: [0,3DD2) qkv rows; [3DD2,4DD2) wo; [4DD2,8DD2) w1t; [8DD2,12DD2) w2t
__global__ __launch_bounds__(256) void transpose_layer(
    const float* __restrict__ wq, const float* __restrict__ wk,
    const float* __restrict__ wv, const float* __restrict__ wo,
    const float* __restrict__ w1, const float* __restrict__ w2,
    unsigned short* __restrict__ wt)
{
    __shared__ float tile[32][33];
    const size_t DD2 = (size_t)DD * DD;
    int bid = blockIdx.x;
    const float* src; unsigned short* dst; int K, N, n0, k0;
    if (bid < 4096) {
        int r = bid >> 10, t = bid & 1023;
        src = (r == 0) ? wq : (r == 1) ? wk : (r == 2) ? wv : wo;
        dst = wt + (size_t)r * DD2; K = DD; N = DD;
        n0 = (t & 31) * 32; k0 = (t >> 5) * 32;
    } else if (bid < 8192) {
        int t = bid - 4096;
        src = w1; dst = wt + 4 * DD2; K = DD; N = 4 * DD;
        n0 = (t & 127) * 32; k0 = (t >> 7) * 32;
    } else {
        int t = bid - 8192;
        src = w2; dst = wt + 8 * DD2; K = 4 * DD; N = DD;
        n0 = (t & 31) * 32; k0 = (t >> 5) * 32;
    }
    int tx = threadIdx.x & 31, ty = threadIdx.x >> 5;
    #pragma unroll
    for (int i = 0; i < 4; i++)
        tile[ty + i*8][tx] = src[(size_t)(k0 + ty + i*8) * N + n0 + tx];
    __syncthreads();
    #pragma unroll
    for (int i = 0; i < 4; i++)
        dst[(size_t)(n0 + ty + i*8) * K + k0 + tx] = f2bf(tile[tx][ty + i*8]);
}

// head: single 1024x1024 transpose
__global__ __launch_bounds__(256) void transpose_bf16(
    const float* __restrict__ W, unsigned short* __restrict__ Wt, int K, int N)
{
    __shared__ float tile[32][33];
    int n0 = blockIdx.x * 32, k0 = blockIdx.y * 32;
    int tx = threadIdx.x & 31, ty = threadIdx.x >> 5;
    #pragma unroll
    for (int i = 0; i < 4; i++)
        tile[ty + i*8][tx] = W[(size_t)(k0 + ty + i*8) * N + n0 + tx];
    __syncthreads();
    #pragma unroll
    for (int i = 0; i < 4; i++)
        Wt[(size_t)(n0 + ty + i*8) * K + k0 + tx] = f2bf(tile[tx][ty + i*8]);
}

// ---------------------------------------------------------------- MFMA GEMM
// C[M,N] = act(A[M,K] @ Bt[N,K]^T + bias) (+ res). 128x128 tile, BK=32,
// register-staged double-buffered LDS pipeline (1 barrier / K-step),
// XCD-aware 1D grid swizzle. M fixed = 4096 (32 m-blocks).
template<int ACT, int RES, int OUTBF>
__global__ __launch_bounds__(256) void mfma_gemm(
    const unsigned short* __restrict__ A, const unsigned short* __restrict__ Bt,
    const float* __restrict__ bias, const float* __restrict__ res,
    void* __restrict__ Cv, int M, int N, int K)
{
    __shared__ unsigned short As[2][128*32];
    __shared__ unsigned short Bs[2][128*32];
    const int tid = threadIdx.x;
    const int wave = tid >> 6, lane = tid & 63;
    const int quad = lane >> 4, lc = lane & 15;

    // XCD swizzle: xcd gets m-band [xcd*4, xcd*4+4), m-fastest within XCD
    const int bid = blockIdx.x;
    const int xcd = bid & 7;
    const int j = bid >> 3;
    const int m0 = (xcd * 4 + (j & 3)) << 7;
    const int n0 = (j >> 2) << 7;

    // staging: thread t loads rows (t>>2) and 64+(t>>2), k-chunk (t&3)*8
    const int srow = tid >> 2, scol = (tid & 3) * 8;
    const unsigned short* Ag = A  + (size_t)(m0 + srow) * K + scol;
    const unsigned short* Bg = Bt + (size_t)(n0 + srow) * K + scol;
    const int lds_lo = srow * 32 + scol, lds_hi = (64 + srow) * 32 + scol;

    const int wm = (wave & 1) * 64, wn = (wave >> 1) * 64;

    floatx4 acc[4][4];
    #pragma unroll
    for (int i = 0; i < 4; i++)
        #pragma unroll
        for (int jj = 0; jj < 4; jj++) acc[i][jj] = (floatx4)0.0f;

    // prologue: prefetch tile 0
    uint4 pa0 = *(const uint4*)(Ag);
    uint4 pa1 = *(const uint4*)(Ag + (size_t)64 * K);
    uint4 pb0 = *(const uint4*)(Bg);
    uint4 pb1 = *(const uint4*)(Bg + (size_t)64 * K);

    int cur = 0;
    for (int k0 = 0; k0 < K; k0 += 32) {
        *(uint4*)&As[cur][lds_lo] = pa0;
        *(uint4*)&As[cur][lds_hi] = pa1;
        *(uint4*)&Bs[cur][lds_lo] = pb0;
        *(uint4*)&Bs[cur][lds_hi] = pb1;
        __syncthreads();
        if (k0 + 32 < K) {
            pa0 = *(const uint4*)(Ag + k0 + 32);
            pa1 = *(const uint4*)(Ag + k0 + 32 + (size_t)64 * K);
            pb0 = *(const uint4*)(Bg + k0 + 32);
            pb1 = *(const uint4*)(Bg + k0 + 32 + (size_t)64 * K);
        }
        bf16x8 af[4], bfr[4];
        #pragma unroll
        for (int i = 0; i < 4; i++)
            af[i] = *(const bf16x8*)&As[cur][(wm + i*16 + lc)*32 + quad*8];
        #pragma unroll
        for (int jj = 0; jj < 4; jj++)
            bfr[jj] = *(const bf16x8*)&Bs[cur][(wn + jj*16 + lc)*32 + quad*8];
        #pragma unroll
        for (int i = 0; i < 4; i++)
            #pragma unroll
            for (int jj = 0; jj < 4; jj++)
                acc[i][jj] = __builtin_amdgcn_mfma_f32_16x16x32_bf16(af[i], bfr[jj], acc[i][jj], 0, 0, 0);
        cur ^= 1;
    }

    #pragma unroll
    for (int jj = 0; jj < 4; jj++) {
        int n = n0 + wn + jj*16 + lc;
        float bv = bias ? bias[n] : 0.0f;
        #pragma unroll
        for (int i = 0; i < 4; i++) {
            int mbase = m0 + wm + i*16 + quad*4;
            #pragma unroll
            for (int r = 0; r < 4; r++) {
                int m = mbase + r;
                float v = acc[i][jj][r] + bv;
                if (ACT) v = 0.5f * v * (1.0f + erff(v * 0.70710678118654752f));
                if (RES) v += res[(size_t)m * N + n];
                if (OUTBF) ((unsigned short*)Cv)[(size_t)m * N + n] = f2bf(v);
                else       ((float*)Cv)[(size_t)m * N + n] = v;
            }
        }
    }
}

// ---------------------------------------------------------------- flash attention (bf16 MFMA)
// grid (T/64, B*H). block 256 = 4 waves. qkv packed [B*T][3072]: q|k|v.
#define LSTR 88
__global__ __launch_bounds__(256) void attn_mfma(
    const unsigned short* __restrict__ qkv, unsigned short* __restrict__ y)
{
    __shared__ unsigned short Qs[64*LSTR];
    __shared__ unsigned short Ks[64*LSTR];   // reused as V^T [dh][s]
    __shared__ unsigned short Ps[64*LSTR];
    const int tid = threadIdx.x, wave = tid >> 6, lane = tid & 63;
    const int quad = lane >> 4, lc = lane & 15;
    const int t0 = blockIdx.x * 64;
    const int b = blockIdx.y >> 4, h = blockIdx.y & 15;

    const unsigned short* q = qkv;
    const unsigned short* k = qkv + DD;
    const unsigned short* v = qkv + 2*DD;

    const size_t rowbase = (size_t)b * TT;
    const int sr = tid >> 2, sc = (tid & 3) * 16;

    {   // stage Q [64 t][64 dh]
        const unsigned short* src = q + (rowbase + t0 + sr) * QKVLD + h*DHH + sc;
        *(uint4*)&Qs[sr*LSTR + sc]     = *(const uint4*)src;
        *(uint4*)&Qs[sr*LSTR + sc + 8] = *(const uint4*)(src + 8);
    }

    float m_r[4], l_r[4];
    floatx4 o_acc[4];
    #pragma unroll
    for (int r = 0; r < 4; r++) { m_r[r] = -1e30f; l_r[r] = 0.0f; }
    #pragma unroll
    for (int f = 0; f < 4; f++) o_acc[f] = (floatx4)0.0f;

    for (int s0 = 0; s0 < TT; s0 += 64) {
        __syncthreads();
        {   // stage K [64 s][64 dh]
            const unsigned short* src = k + (rowbase + s0 + sr) * QKVLD + h*DHH + sc;
            *(uint4*)&Ks[sr*LSTR + sc]     = *(const uint4*)src;
            *(uint4*)&Ks[sr*LSTR + sc + 8] = *(const uint4*)(src + 8);
        }
        __syncthreads();

        floatx4 s[4];
        #pragma unroll
        for (int f = 0; f < 4; f++) s[f] = (floatx4)0.0f;
        #pragma unroll
        for (int c = 0; c < 2; c++) {
            bf16x8 aq = *(const bf16x8*)&Qs[(wave*16 + lc)*LSTR + c*32 + quad*8];
            #pragma unroll
            for (int f = 0; f < 4; f++) {
                bf16x8 bk = *(const bf16x8*)&Ks[(f*16 + lc)*LSTR + c*32 + quad*8];
                s[f] = __builtin_amdgcn_mfma_f32_16x16x32_bf16(aq, bk, s[f], 0, 0, 0);
            }
        }

        #pragma unroll
        for (int r = 0; r < 4; r++) {
            float mt = fmaxf(fmaxf(s[0][r], s[1][r]), fmaxf(s[2][r], s[3][r])) * 0.125f;
            #pragma unroll
            for (int d = 1; d < 16; d <<= 1) mt = fmaxf(mt, __shfl_xor(mt, d, 64));
            float mn = fmaxf(m_r[r], mt);
            float alpha = __expf(m_r[r] - mn);
            m_r[r] = mn;
            float rs = 0.0f;
            #pragma unroll
            for (int f = 0; f < 4; f++) {
                float p = __expf(s[f][r] * 0.125f - mn);
                s[f][r] = p;
                rs += p;
            }
            #pragma unroll
            for (int d = 1; d < 16; d <<= 1) rs += __shfl_xor(rs, d, 64);
            l_r[r] = l_r[r] * alpha + rs;
            #pragma unroll
            for (int f = 0; f < 4; f++) o_acc[f][r] *= alpha;
        }

        #pragma unroll
        for (int f = 0; f < 4; f++)
            #pragma unroll
            for (int r = 0; r < 4; r++)
                Ps[(wave*16 + quad*4 + r)*LSTR + f*16 + lc] = f2bf(s[f][r]);

        __syncthreads();
        {   // stage V^T [64 dh][64 s] into Ks
            const unsigned short* src = v + (rowbase + s0 + sr) * QKVLD + h*DHH + sc;
            uint4 v0 = *(const uint4*)src;
            uint4 v1 = *(const uint4*)(src + 8);
            unsigned short tmp[16];
            *(uint4*)&tmp[0] = v0;
            *(uint4*)&tmp[8] = v1;
            #pragma unroll
            for (int e = 0; e < 16; e++)
                Ks[(sc + e)*LSTR + sr] = tmp[e];
        }
        __syncthreads();

        #pragma unroll
        for (int c = 0; c < 2; c++) {
            bf16x8 ap = *(const bf16x8*)&Ps[(wave*16 + lc)*LSTR + c*32 + quad*8];
            #pragma unroll
            for (int f = 0; f < 4; f++) {
                bf16x8 bv = *(const bf16x8*)&Ks[(f*16 + lc)*LSTR + c*32 + quad*8];
                o_acc[f] = __builtin_amdgcn_mfma_f32_16x16x32_bf16(ap, bv, o_acc[f], 0, 0, 0);
            }
        }
    }

    unsigned short* yg = y + (rowbase + t0) * DD + h*DHH;
    #pragma unroll
    for (int f = 0; f < 4; f++)
        #pragma unroll
        for (int r = 0; r < 4; r++)
            yg[(size_t)(wave*16 + quad*4 + r) * DD + f*16 + lc] = f2bf(o_acc[f][r] / l_r[r]);
}

// ---------------------------------------------------------------- launch
extern "C" void kernel_launch(void* const* d_in, const int* in_sizes, int n_in,
                              void* d_out, int out_size, void* d_ws, size_t ws_size,
                              hipStream_t stream)
{
    const float* seq    = (const float*)d_in[0];
    const float* pos    = (const float*)d_in[1];
    const float* ln1_g  = (const float*)d_in[2];
    const float* ln1_b  = (const float*)d_in[3];
    const float* wq     = (const float*)d_in[4];
    const float* bq     = (const float*)d_in[5];
    const float* wk     = (const float*)d_in[6];
    const float* bk     = (const float*)d_in[7];
    const float* wv     = (const float*)d_in[8];
    const float* bv     = (const float*)d_in[9];
    const float* wo     = (const float*)d_in[10];
    const float* bo     = (const float*)d_in[11];
    const float* ln2_g  = (const float*)d_in[12];
    const float* ln2_b  = (const float*)d_in[13];
    const float* w1     = (const float*)d_in[14];
    const float* b1     = (const float*)d_in[15];
    const float* w2     = (const float*)d_in[16];
    const float* b2     = (const float*)d_in[17];
    const float* lnf_g  = (const float*)d_in[18];
    const float* lnf_b  = (const float*)d_in[19];
    const float* w_head = (const float*)d_in[20];
    float* out = (float*)d_out;

    const size_t MSZ = (size_t)MM * DD;
    float* x            = (float*)d_ws;                 // 16 MB fp32
    unsigned short* h   = (unsigned short*)(x + MSZ);   // 8 MB bf16
    unsigned short* qkv = h + MSZ;                      // [4096][3072] bf16, 24 MB
    unsigned short* ub  = qkv + (size_t)MM * QKVLD;     // [4096][4096] bf16, 32 MB
    unsigned short* wt  = ub + (size_t)MM * 4 * DD;     // 12M el, 24 MB
    unsigned short* wto = wt + (size_t)3*DD*DD;
    unsigned short* wt1 = wt + (size_t)4*DD*DD;         // [4096][1024]
    unsigned short* wt2 = wt + (size_t)8*DD*DD;         // [1024][4096]
    float* bqkv         = (float*)(wt + (size_t)12*DD*DD);  // [L][3072] fp32

    dim3 blk(256);
    dim3 g1(32*8);      // N=1024: 256 blocks (1D swizzled)
    dim3 gq(32*24);     // N=3072: 768 blocks
    dim3 g4(32*32);     // N=4096: 1024 blocks
    dim3 tsq(32, 32);
    dim3 ag(16, 64);

    add_pos_kernel<<<4096, blk, 0, stream>>>(seq, pos, x);
    concat_bias_kernel<<<LL*QKVLD/256, blk, 0, stream>>>(bq, bk, bv, bqkv);

    for (int l = 0; l < LL; l++) {
        const size_t wofs  = (size_t)l * DD * DD;
        const size_t bofs  = (size_t)l * DD;
        const size_t w1ofs = (size_t)l * DD * 4 * DD;
        const size_t b1ofs = (size_t)l * 4 * DD;

        transpose_layer<<<12288, blk, 0, stream>>>(
            wq + wofs, wk + wofs, wv + wofs, wo + wofs, w1 + w1ofs, w2 + w1ofs, wt);

        ln_kernel<<<MM, blk, 0, stream>>>(x, ln1_g + bofs, ln1_b + bofs, h);
        mfma_gemm<0,0,1><<<gq, blk, 0, stream>>>(h, wt, bqkv + (size_t)l*QKVLD, nullptr, qkv, MM, QKVLD, DD);
        attn_mfma<<<ag, blk, 0, stream>>>(qkv, h);
        mfma_gemm<0,1,0><<<g1, blk, 0, stream>>>(h, wto, bo + bofs, x, x, MM, DD, DD);
        ln_kernel<<<MM, blk, 0, stream>>>(x, ln2_g + bofs, ln2_b + bofs, h);
        mfma_gemm<1,0,1><<<g4, blk, 0, stream>>>(h, wt1, b1 + b1ofs, nullptr, ub, MM, 4*DD, DD);
        mfma_gemm<0,1,0><<<g1, blk, 0, stream>>>(ub, wt2, b2 + bofs, x, x, MM, DD, 4*DD);
    }

    ln_kernel<<<MM, blk, 0, stream>>>(x, lnf_g, lnf_b, h);
    transpose_bf16<<<tsq, blk, 0, stream>>>(w_head, wt, DD, DD);
    mfma_gemm<0,0,0><<<g1, blk, 0, stream>>>(h, wt, nullptr, nullptr, out, MM, DD, DD);
}